// Round 1
// baseline (1909.108 us; speedup 1.0000x reference)
//
#include <hip/hip_runtime.h>
#include <math.h>

#define B_ 2
#define S_ 1024
#define HID_ 1024
#define NH_ 16
#define D_ 64
#define M_ (B_ * S_)   // 2048
#define CLIP_ 5.0f
#define EPS_ 1e-6f

// ---------------------------------------------------------------------------
// Tiled f32 GEMM: C[M,N] = A[M,K] @ W[K,N], all row-major.
// Tile 64x128, TILE_K=16, 256 threads, 4x8 micro-tile per thread.
// ---------------------------------------------------------------------------
__global__ __launch_bounds__(256) void gemm_f32_64x128(
    const float* __restrict__ A, const float* __restrict__ W,
    float* __restrict__ C, int M, int N, int K)
{
    __shared__ __align__(16) float As[16][64];     // [k][m]
    __shared__ __align__(16) float Ws[16][128];    // [k][n]

    const int t  = threadIdx.x;
    const int bm = blockIdx.y * 64;
    const int bn = blockIdx.x * 128;

    // micro-tile coords: rows bm+tr..tr+3 ; cols bn+tc4..+3 and bn+64+tc4..+3
    const int tr  = (t >> 4) * 4;     // 0..60
    const int tc4 = (t & 15) * 4;     // 0..60

    float acc[4][8];
#pragma unroll
    for (int i = 0; i < 4; ++i)
#pragma unroll
        for (int j = 0; j < 8; ++j) acc[i][j] = 0.f;

    // A staging: 64 rows x 16 k = 1024 floats -> 1 float4 per thread
    const int lam = t >> 2;          // 0..63 row
    const int lak = (t & 3) * 4;     // 0,4,8,12
    // W staging: 16 k x 128 n = 2048 floats -> 2 float4 per thread
    const int lwk = t >> 4;          // 0..15
    const int lwn = (t & 15) * 8;    // 0..120

    for (int k0 = 0; k0 < K; k0 += 16) {
        float4 av  = *(const float4*)(A + (size_t)(bm + lam) * K + k0 + lak);
        float4 wv0 = *(const float4*)(W + (size_t)(k0 + lwk) * N + bn + lwn);
        float4 wv1 = *(const float4*)(W + (size_t)(k0 + lwk) * N + bn + lwn + 4);
        As[lak + 0][lam] = av.x;
        As[lak + 1][lam] = av.y;
        As[lak + 2][lam] = av.z;
        As[lak + 3][lam] = av.w;
        *(float4*)&Ws[lwk][lwn]     = wv0;
        *(float4*)&Ws[lwk][lwn + 4] = wv1;
        __syncthreads();
#pragma unroll
        for (int kk = 0; kk < 16; ++kk) {
            float4 a4 = *(const float4*)&As[kk][tr];          // broadcast in 16-lane groups
            float4 b0 = *(const float4*)&Ws[kk][tc4];         // lanes cover 0..63 contig
            float4 b1 = *(const float4*)&Ws[kk][64 + tc4];
            float aa[4] = {a4.x, a4.y, a4.z, a4.w};
            float bb[8] = {b0.x, b0.y, b0.z, b0.w, b1.x, b1.y, b1.z, b1.w};
#pragma unroll
            for (int i = 0; i < 4; ++i)
#pragma unroll
                for (int j = 0; j < 8; ++j)
                    acc[i][j] += aa[i] * bb[j];
        }
        __syncthreads();
    }

#pragma unroll
    for (int i = 0; i < 4; ++i) {
        float4 o0 = make_float4(acc[i][0], acc[i][1], acc[i][2], acc[i][3]);
        float4 o1 = make_float4(acc[i][4], acc[i][5], acc[i][6], acc[i][7]);
        *(float4*)(C + (size_t)(bm + tr + i) * N + bn + tc4)      = o0;
        *(float4*)(C + (size_t)(bm + tr + i) * N + bn + 64 + tc4) = o1;
    }
}

// ---------------------------------------------------------------------------
// alpha/beta: sigmoid(x @ Wa + ba), sigmoid(x @ Wb + bb).  [M,16] each.
// One thread per (row, col) with col in 0..31 (0..15 -> alpha, 16..31 -> beta)
// ---------------------------------------------------------------------------
__global__ __launch_bounds__(256) void ab_kernel(
    const float* __restrict__ x,
    const float* __restrict__ Wa, const float* __restrict__ ba,
    const float* __restrict__ Wb, const float* __restrict__ bbias,
    float* __restrict__ alpha, float* __restrict__ beta)
{
    int gid = blockIdx.x * 256 + threadIdx.x;   // 0 .. M*32-1
    int row = gid >> 5;
    int c   = gid & 31;
    const float* w = (c < 16) ? (Wa + c) : (Wb + (c - 16));
    float bias     = (c < 16) ? ba[c] : bbias[c - 16];
    const float* xr = x + (size_t)row * HID_;
    float s = 0.f;
#pragma unroll 4
    for (int k = 0; k < HID_; ++k) s += xr[k] * w[(size_t)k * NH_];
    float val = 1.f / (1.f + expf(-(s + bias)));
    if (c < 16) alpha[row * NH_ + c]       = val;
    else        beta[row * NH_ + (c - 16)] = val;
}

// ---------------------------------------------------------------------------
// In-place: q,k l2-normalized per 64-element head group; v = tanh(v).
// 64-element group == one full wave (D=64 == wavefront), so reduction is shfl.
// ---------------------------------------------------------------------------
__global__ __launch_bounds__(256) void norm_kernel(
    float* __restrict__ q, float* __restrict__ k, float* __restrict__ v)
{
    int gid = blockIdx.x * 256 + threadIdx.x;   // 0 .. M*HID-1

    float qv = q[gid];
    float qs = qv * qv;
#pragma unroll
    for (int off = 1; off < 64; off <<= 1) qs += __shfl_xor(qs, off);
    q[gid] = qv / fmaxf(sqrtf(qs), EPS_);

    float kv = k[gid];
    float ks = kv * kv;
#pragma unroll
    for (int off = 1; off < 64; off <<= 1) ks += __shfl_xor(ks, off);
    k[gid] = kv / fmaxf(sqrtf(ks), EPS_);

    v[gid] = tanhf(v[gid]);
}

// ---------------------------------------------------------------------------
// Sequential scan. One wave (64 threads) per (b,h); lane = state row v.
// State row (64 cols) lives in registers. k_t kept in registers for the
// update loop; q_t/k_t broadcast via LDS float4 reads.
// ---------------------------------------------------------------------------
__global__ __launch_bounds__(64) void scan_kernel(
    const float* __restrict__ qn, const float* __restrict__ kn,
    const float* __restrict__ vt,
    const float* __restrict__ alpha, const float* __restrict__ beta,
    const int* __restrict__ mask,
    const float* __restrict__ state0,
    float* __restrict__ y, float* __restrict__ state_out)
{
    const int bh   = blockIdx.x;          // 0..31
    const int b    = bh / NH_;
    const int h    = bh % NH_;
    const int lane = threadIdx.x;         // row v

    float st[64];
    {
        const float4* s0 = (const float4*)(state0 + ((size_t)bh * 64 + lane) * 64);
#pragma unroll
        for (int j4 = 0; j4 < 16; ++j4) {
            float4 s = s0[j4];
            st[4 * j4 + 0] = s.x; st[4 * j4 + 1] = s.y;
            st[4 * j4 + 2] = s.z; st[4 * j4 + 3] = s.w;
        }
    }

    __shared__ __align__(16) float lk[64];
    __shared__ __align__(16) float lq[64];

    size_t base = ((size_t)b * S_) * HID_ + h * 64 + lane;   // element index for t=0
    int    arow = b * S_;                                     // alpha/beta/mask row for t=0

    // prologue loads for t=0
    float kj = kn[base];
    float qj = qn[base];
    float vj = vt[base];
    float a  = alpha[(size_t)arow * NH_ + h];
    float be = beta [(size_t)arow * NH_ + h];
    int   m  = mask[arow];

    for (int t = 0; t < S_; ++t) {
        lk[lane] = kj;
        lq[lane] = qj;
        __syncthreads();

        float vcur = vj, acur = a, becur = be;
        int   mcur = m;

        // prefetch t+1 while computing
        if (t + 1 < S_) {
            size_t base2 = base + HID_;
            int    arow2 = arow + 1;
            kj = kn[base2];
            qj = qn[base2];
            vj = vt[base2];
            a  = alpha[(size_t)arow2 * NH_ + h];
            be = beta [(size_t)arow2 * NH_ + h];
            m  = mask[arow2];
        }

        // read = st . k   (keep k in regs for the update loop)
        float kreg[64];
        float r0 = 0.f, r1 = 0.f, r2 = 0.f, r3 = 0.f;
#pragma unroll
        for (int j4 = 0; j4 < 16; ++j4) {
            float4 k4 = ((const float4*)lk)[j4];
            kreg[4 * j4 + 0] = k4.x; kreg[4 * j4 + 1] = k4.y;
            kreg[4 * j4 + 2] = k4.z; kreg[4 * j4 + 3] = k4.w;
            r0 += st[4 * j4 + 0] * k4.x;
            r1 += st[4 * j4 + 1] * k4.y;
            r2 += st[4 * j4 + 2] * k4.z;
            r3 += st[4 * j4 + 3] * k4.w;
        }
        float read = (r0 + r1) + (r2 + r3);
        float c    = becur * (vcur - read);

        if (mcur) {
#pragma unroll
            for (int j = 0; j < 64; ++j) {
                float nv = acur * st[j] + c * kreg[j];
                st[j] = fminf(fmaxf(nv, -CLIP_), CLIP_);
            }
        }

        float y0 = 0.f, y1 = 0.f, y2 = 0.f, y3 = 0.f;
#pragma unroll
        for (int j4 = 0; j4 < 16; ++j4) {
            float4 q4 = ((const float4*)lq)[j4];
            y0 += st[4 * j4 + 0] * q4.x;
            y1 += st[4 * j4 + 1] * q4.y;
            y2 += st[4 * j4 + 2] * q4.z;
            y3 += st[4 * j4 + 3] * q4.w;
        }
        float yv = mcur ? ((y0 + y1) + (y2 + y3)) : 0.f;
        y[base + (size_t)t * 0 /*base already advances*/] = yv;   // base is for step t until we advance

        base += HID_;
        arow += 1;
        __syncthreads();
    }

    float4* so = (float4*)(state_out + ((size_t)bh * 64 + lane) * 64);
#pragma unroll
    for (int j4 = 0; j4 < 16; ++j4)
        so[j4] = make_float4(st[4 * j4 + 0], st[4 * j4 + 1],
                             st[4 * j4 + 2], st[4 * j4 + 3]);
}

// ---------------------------------------------------------------------------
// launch
// ---------------------------------------------------------------------------
extern "C" void kernel_launch(void* const* d_in, const int* in_sizes, int n_in,
                              void* d_out, int out_size, void* d_ws, size_t ws_size,
                              hipStream_t stream)
{
    (void)in_sizes; (void)n_in; (void)out_size; (void)ws_size;

    const float* x      = (const float*)d_in[0];
    const float* Wq     = (const float*)d_in[1];
    const float* Wk     = (const float*)d_in[2];
    const float* Wv     = (const float*)d_in[3];
    const float* Wa     = (const float*)d_in[4];
    const float* ba     = (const float*)d_in[5];
    const float* Wb     = (const float*)d_in[6];
    const float* bb     = (const float*)d_in[7];
    const float* Wo     = (const float*)d_in[8];
    const float* state0 = (const float*)d_in[9];
    const int*   mask   = (const int*)d_in[10];

    float* out = (float*)d_out;
    float* ws  = (float*)d_ws;

    float* q     = ws;                 // 2,097,152 floats
    float* k     = ws + 2097152;
    float* v     = ws + 4194304;
    float* alpha = ws + 6291456;       // 32,768
    float* beta  = ws + 6324224;
    float* y     = ws + 6356992;       // 2,097,152

    dim3 gg(8, 32);  // N/128, M/64
    gemm_f32_64x128<<<gg, 256, 0, stream>>>(x, Wq, q, M_, HID_, HID_);
    gemm_f32_64x128<<<gg, 256, 0, stream>>>(x, Wk, k, M_, HID_, HID_);
    gemm_f32_64x128<<<gg, 256, 0, stream>>>(x, Wv, v, M_, HID_, HID_);
    ab_kernel<<<M_ * 32 / 256, 256, 0, stream>>>(x, Wa, ba, Wb, bb, alpha, beta);
    norm_kernel<<<M_ * HID_ / 256, 256, 0, stream>>>(q, k, v);
    scan_kernel<<<B_ * NH_, 64, 0, stream>>>(q, k, v, alpha, beta, mask, state0,
                                             y, out + (size_t)M_ * HID_);
    gemm_f32_64x128<<<gg, 256, 0, stream>>>(y, Wo, out, M_, HID_, HID_);
}

// Round 2
// 998.143 us; speedup vs baseline: 1.9127x; 1.9127x over previous
//
#include <hip/hip_runtime.h>
#include <math.h>

#define B_ 2
#define S_ 1024
#define HID_ 1024
#define NH_ 16
#define D_ 64
#define M_ (B_ * S_)   // 2048
#define CLIP_ 5.0f
#define EPS_ 1e-6f

// ---------------------------------------------------------------------------
// Fused Q/K/V GEMM: z in {0,1,2} selects (Wq->q, Wk->k, Wv->v).
// Tile 64x128, TILE_K=16, 256 threads, 4x8 micro-tile. As padded to 68 to
// break the 4-way bank conflict on the transpose store (2-way is free).
// ---------------------------------------------------------------------------
__global__ __launch_bounds__(256) void gemm_qkv(
    const float* __restrict__ A,
    const float* __restrict__ W0, const float* __restrict__ W1, const float* __restrict__ W2,
    float* __restrict__ C0, float* __restrict__ C1, float* __restrict__ C2)
{
    const int z = blockIdx.z;
    const float* W = (z == 0) ? W0 : (z == 1) ? W1 : W2;
    float*       C = (z == 0) ? C0 : (z == 1) ? C1 : C2;

    __shared__ __align__(16) float As[16][68];
    __shared__ __align__(16) float Ws[16][128];

    const int t  = threadIdx.x;
    const int bm = blockIdx.y * 64;
    const int bn = blockIdx.x * 128;

    const int tr  = (t >> 4) * 4;
    const int tc4 = (t & 15) * 4;

    float acc[4][8];
#pragma unroll
    for (int i = 0; i < 4; ++i)
#pragma unroll
        for (int j = 0; j < 8; ++j) acc[i][j] = 0.f;

    const int lam = t >> 2;
    const int lak = (t & 3) * 4;
    const int lwk = t >> 4;
    const int lwn = (t & 15) * 8;

    for (int k0 = 0; k0 < HID_; k0 += 16) {
        float4 av  = *(const float4*)(A + (size_t)(bm + lam) * HID_ + k0 + lak);
        float4 wv0 = *(const float4*)(W + (size_t)(k0 + lwk) * HID_ + bn + lwn);
        float4 wv1 = *(const float4*)(W + (size_t)(k0 + lwk) * HID_ + bn + lwn + 4);
        As[lak + 0][lam] = av.x;
        As[lak + 1][lam] = av.y;
        As[lak + 2][lam] = av.z;
        As[lak + 3][lam] = av.w;
        *(float4*)&Ws[lwk][lwn]     = wv0;
        *(float4*)&Ws[lwk][lwn + 4] = wv1;
        __syncthreads();
#pragma unroll
        for (int kk = 0; kk < 16; ++kk) {
            float4 a4 = *(const float4*)&As[kk][tr];
            float4 b0 = *(const float4*)&Ws[kk][tc4];
            float4 b1 = *(const float4*)&Ws[kk][64 + tc4];
            float aa[4] = {a4.x, a4.y, a4.z, a4.w};
            float bb[8] = {b0.x, b0.y, b0.z, b0.w, b1.x, b1.y, b1.z, b1.w};
#pragma unroll
            for (int i = 0; i < 4; ++i)
#pragma unroll
                for (int j = 0; j < 8; ++j)
                    acc[i][j] += aa[i] * bb[j];
        }
        __syncthreads();
    }

#pragma unroll
    for (int i = 0; i < 4; ++i) {
        float4 o0 = make_float4(acc[i][0], acc[i][1], acc[i][2], acc[i][3]);
        float4 o1 = make_float4(acc[i][4], acc[i][5], acc[i][6], acc[i][7]);
        *(float4*)(C + (size_t)(bm + tr + i) * HID_ + bn + tc4)      = o0;
        *(float4*)(C + (size_t)(bm + tr + i) * HID_ + bn + 64 + tc4) = o1;
    }
}

// ---------------------------------------------------------------------------
// Wo GEMM: 64x64 tile, 512 blocks -> 2 blocks/CU. 4x4 micro-tile.
// ---------------------------------------------------------------------------
__global__ __launch_bounds__(256) void gemm_wo(
    const float* __restrict__ A, const float* __restrict__ W,
    float* __restrict__ C)
{
    __shared__ __align__(16) float As[16][68];
    __shared__ __align__(16) float Ws[16][64];

    const int t  = threadIdx.x;
    const int bm = blockIdx.y * 64;
    const int bn = blockIdx.x * 64;

    const int tr  = (t >> 4) * 4;
    const int tc4 = (t & 15) * 4;

    float acc[4][4];
#pragma unroll
    for (int i = 0; i < 4; ++i)
#pragma unroll
        for (int j = 0; j < 4; ++j) acc[i][j] = 0.f;

    const int lam = t >> 2;
    const int lak = (t & 3) * 4;
    const int lwk = t >> 4;
    const int lwn = (t & 15) * 4;

    for (int k0 = 0; k0 < HID_; k0 += 16) {
        float4 av = *(const float4*)(A + (size_t)(bm + lam) * HID_ + k0 + lak);
        float4 wv = *(const float4*)(W + (size_t)(k0 + lwk) * HID_ + bn + lwn);
        As[lak + 0][lam] = av.x;
        As[lak + 1][lam] = av.y;
        As[lak + 2][lam] = av.z;
        As[lak + 3][lam] = av.w;
        *(float4*)&Ws[lwk][lwn] = wv;
        __syncthreads();
#pragma unroll
        for (int kk = 0; kk < 16; ++kk) {
            float4 a4 = *(const float4*)&As[kk][tr];
            float4 b4 = *(const float4*)&Ws[kk][tc4];
            float aa[4] = {a4.x, a4.y, a4.z, a4.w};
            float bb[4] = {b4.x, b4.y, b4.z, b4.w};
#pragma unroll
            for (int i = 0; i < 4; ++i)
#pragma unroll
                for (int j = 0; j < 4; ++j)
                    acc[i][j] += aa[i] * bb[j];
        }
        __syncthreads();
    }

#pragma unroll
    for (int i = 0; i < 4; ++i)
        *(float4*)(C + (size_t)(bm + tr + i) * HID_ + bn + tc4) =
            make_float4(acc[i][0], acc[i][1], acc[i][2], acc[i][3]);
}

// ---------------------------------------------------------------------------
// alpha/beta projections (unchanged)
// ---------------------------------------------------------------------------
__global__ __launch_bounds__(256) void ab_kernel(
    const float* __restrict__ x,
    const float* __restrict__ Wa, const float* __restrict__ ba,
    const float* __restrict__ Wb, const float* __restrict__ bbias,
    float* __restrict__ alpha, float* __restrict__ beta)
{
    int gid = blockIdx.x * 256 + threadIdx.x;
    int row = gid >> 5;
    int c   = gid & 31;
    const float* w = (c < 16) ? (Wa + c) : (Wb + (c - 16));
    float bias     = (c < 16) ? ba[c] : bbias[c - 16];
    const float* xr = x + (size_t)row * HID_;
    float s = 0.f;
#pragma unroll 4
    for (int k = 0; k < HID_; ++k) s += xr[k] * w[(size_t)k * NH_];
    float val = 1.f / (1.f + expf(-(s + bias)));
    if (c < 16) alpha[row * NH_ + c]       = val;
    else        beta[row * NH_ + (c - 16)] = val;
}

// ---------------------------------------------------------------------------
// l2norm(q), l2norm(k), tanh(v) (unchanged)
// ---------------------------------------------------------------------------
__global__ __launch_bounds__(256) void norm_kernel(
    float* __restrict__ q, float* __restrict__ k, float* __restrict__ v)
{
    int gid = blockIdx.x * 256 + threadIdx.x;

    float qv = q[gid];
    float qs = qv * qv;
#pragma unroll
    for (int off = 1; off < 64; off <<= 1) qs += __shfl_xor(qs, off);
    q[gid] = qv / fmaxf(sqrtf(qs), EPS_);

    float kv = k[gid];
    float ks = kv * kv;
#pragma unroll
    for (int off = 1; off < 64; off <<= 1) ks += __shfl_xor(ks, off);
    k[gid] = kv / fmaxf(sqrtf(ks), EPS_);

    v[gid] = tanhf(v[gid]);
}

// ---------------------------------------------------------------------------
// Scan, redesigned: one wave per (b,h,v) STATE ROW (2048 independent chains,
// 64x the old parallelism). lane = state column. Per step: shfl-reduce for
// read, elementwise update, shfl-reduce for y. Depth-2 load pipeline.
// ---------------------------------------------------------------------------
__global__ __launch_bounds__(64) void scan_kernel(
    const float* __restrict__ qn, const float* __restrict__ kn,
    const float* __restrict__ vt,
    const float* __restrict__ alpha, const float* __restrict__ beta,
    const int* __restrict__ mask,
    const float* __restrict__ state0,
    float* __restrict__ y, float* __restrict__ state_out)
{
    const int gid  = blockIdx.x;          // (b*NH + h)*64 + v
    const int v    = gid & 63;
    const int bh   = gid >> 6;
    const int b    = bh >> 4;
    const int h    = bh & 15;
    const int lane = threadIdx.x;         // column

    float st = state0[(size_t)gid * 64 + lane];

    const size_t rowbase = (size_t)b * S_ * HID_ + h * 64;
    const float* kp = kn + rowbase + lane;
    const float* qp = qn + rowbase + lane;
    const float* vp = vt + rowbase + v;
    const float* ap = alpha + (size_t)b * S_ * NH_ + h;
    const float* bp = beta  + (size_t)b * S_ * NH_ + h;
    const int*   mp = mask  + b * S_;
    float*       yp = y + rowbase + v;

    // pipeline: regs for steps t (A) and t+1 (B)
    float kA = kp[0],    qA = qp[0],    vA = vp[0];
    float aA = ap[0],    bA = bp[0];
    int   mA = mp[0];
    float kB = kp[HID_], qB = qp[HID_], vB = vp[HID_];
    float aB = ap[NH_],  bB = bp[NH_];
    int   mB = mp[1];

#define STEP(T, kc, qc, vc, ac, bc, mc)                                   \
    {                                                                     \
        float r = st * (kc);                                              \
        r += __shfl_xor(r, 32); r += __shfl_xor(r, 16);                   \
        r += __shfl_xor(r, 8);  r += __shfl_xor(r, 4);                    \
        r += __shfl_xor(r, 2);  r += __shfl_xor(r, 1);                    \
        if (mc) {                                                         \
            float c = (bc) * ((vc) - r);                                  \
            st = fminf(fmaxf((ac) * st + c * (kc), -CLIP_), CLIP_);       \
        }                                                                 \
        float yv = st * (qc);                                             \
        yv += __shfl_xor(yv, 32); yv += __shfl_xor(yv, 16);               \
        yv += __shfl_xor(yv, 8);  yv += __shfl_xor(yv, 4);                \
        yv += __shfl_xor(yv, 2);  yv += __shfl_xor(yv, 1);                \
        if (lane == 0) yp[(size_t)(T) * HID_] = (mc) ? yv : 0.f;          \
    }

    for (int t = 0; t < S_; t += 2) {
        const int t2 = (t + 2 < S_) ? t + 2 : S_ - 1;
        const int t3 = (t + 3 < S_) ? t + 3 : S_ - 1;
        float kA2 = kp[(size_t)t2 * HID_], qA2 = qp[(size_t)t2 * HID_], vA2 = vp[(size_t)t2 * HID_];
        float aA2 = ap[(size_t)t2 * NH_],  bA2 = bp[(size_t)t2 * NH_];
        int   mA2 = mp[t2];
        float kB2 = kp[(size_t)t3 * HID_], qB2 = qp[(size_t)t3 * HID_], vB2 = vp[(size_t)t3 * HID_];
        float aB2 = ap[(size_t)t3 * NH_],  bB2 = bp[(size_t)t3 * NH_];
        int   mB2 = mp[t3];

        STEP(t,     kA, qA, vA, aA, bA, mA);
        STEP(t + 1, kB, qB, vB, aB, bB, mB);

        kA = kA2; qA = qA2; vA = vA2; aA = aA2; bA = bA2; mA = mA2;
        kB = kB2; qB = qB2; vB = vB2; aB = aB2; bB = bB2; mB = mB2;
    }
#undef STEP

    state_out[(size_t)gid * 64 + lane] = st;
}

// ---------------------------------------------------------------------------
// launch
// ---------------------------------------------------------------------------
extern "C" void kernel_launch(void* const* d_in, const int* in_sizes, int n_in,
                              void* d_out, int out_size, void* d_ws, size_t ws_size,
                              hipStream_t stream)
{
    (void)in_sizes; (void)n_in; (void)out_size; (void)ws_size;

    const float* x      = (const float*)d_in[0];
    const float* Wq     = (const float*)d_in[1];
    const float* Wk     = (const float*)d_in[2];
    const float* Wv     = (const float*)d_in[3];
    const float* Wa     = (const float*)d_in[4];
    const float* ba     = (const float*)d_in[5];
    const float* Wb     = (const float*)d_in[6];
    const float* bb     = (const float*)d_in[7];
    const float* Wo     = (const float*)d_in[8];
    const float* state0 = (const float*)d_in[9];
    const int*   mask   = (const int*)d_in[10];

    float* out = (float*)d_out;
    float* ws  = (float*)d_ws;

    float* q     = ws;
    float* k     = ws + 2097152;
    float* v     = ws + 4194304;
    float* alpha = ws + 6291456;
    float* beta  = ws + 6324224;
    float* y     = ws + 6356992;

    dim3 gqkv(8, 32, 3);   // N/128, M/64, {q,k,v}
    gemm_qkv<<<gqkv, 256, 0, stream>>>(x, Wq, Wk, Wv, q, k, v);
    ab_kernel<<<M_ * 32 / 256, 256, 0, stream>>>(x, Wa, ba, Wb, bb, alpha, beta);
    norm_kernel<<<M_ * HID_ / 256, 256, 0, stream>>>(q, k, v);
    scan_kernel<<<B_ * NH_ * D_, 64, 0, stream>>>(q, k, v, alpha, beta, mask, state0,
                                                  y, out + (size_t)M_ * HID_);
    dim3 gwo(16, 32);      // N/64, M/64
    gemm_wo<<<gwo, 256, 0, stream>>>(y, Wo, out);
}

// Round 3
// 594.657 us; speedup vs baseline: 3.2104x; 1.6785x over previous
//
#include <hip/hip_runtime.h>
#include <math.h>

#define B_ 2
#define S_ 1024
#define HID_ 1024
#define NH_ 16
#define D_ 64
#define M_ (B_ * S_)   // 2048
#define CLIP_ 5.0f
#define EPS_ 1e-6f

// ---------------------------------------------------------------------------
// Wave64 sum via DPP (LLVM atomic-optimizer sequence). Result lands in
// lane 63; other lanes hold partial garbage. ~12 VALU ops, no LDS traffic.
// ---------------------------------------------------------------------------
__device__ __forceinline__ float wave_sum_lane63(float x) {
    x += __int_as_float(__builtin_amdgcn_update_dpp(0, __float_as_int(x), 0x111, 0xf, 0xf, true)); // row_shr:1
    x += __int_as_float(__builtin_amdgcn_update_dpp(0, __float_as_int(x), 0x112, 0xf, 0xf, true)); // row_shr:2
    x += __int_as_float(__builtin_amdgcn_update_dpp(0, __float_as_int(x), 0x114, 0xf, 0xf, true)); // row_shr:4
    x += __int_as_float(__builtin_amdgcn_update_dpp(0, __float_as_int(x), 0x118, 0xf, 0xf, true)); // row_shr:8
    x += __int_as_float(__builtin_amdgcn_update_dpp(0, __float_as_int(x), 0x142, 0xa, 0xf, true)); // row_bcast:15
    x += __int_as_float(__builtin_amdgcn_update_dpp(0, __float_as_int(x), 0x143, 0xc, 0xf, true)); // row_bcast:31
    return x;
}

// ---------------------------------------------------------------------------
// Fused Q/K/V GEMM (unchanged from round 1)
// ---------------------------------------------------------------------------
__global__ __launch_bounds__(256) void gemm_qkv(
    const float* __restrict__ A,
    const float* __restrict__ W0, const float* __restrict__ W1, const float* __restrict__ W2,
    float* __restrict__ C0, float* __restrict__ C1, float* __restrict__ C2)
{
    const int z = blockIdx.z;
    const float* W = (z == 0) ? W0 : (z == 1) ? W1 : W2;
    float*       C = (z == 0) ? C0 : (z == 1) ? C1 : C2;

    __shared__ __align__(16) float As[16][68];
    __shared__ __align__(16) float Ws[16][128];

    const int t  = threadIdx.x;
    const int bm = blockIdx.y * 64;
    const int bn = blockIdx.x * 128;

    const int tr  = (t >> 4) * 4;
    const int tc4 = (t & 15) * 4;

    float acc[4][8];
#pragma unroll
    for (int i = 0; i < 4; ++i)
#pragma unroll
        for (int j = 0; j < 8; ++j) acc[i][j] = 0.f;

    const int lam = t >> 2;
    const int lak = (t & 3) * 4;
    const int lwk = t >> 4;
    const int lwn = (t & 15) * 8;

    for (int k0 = 0; k0 < HID_; k0 += 16) {
        float4 av  = *(const float4*)(A + (size_t)(bm + lam) * HID_ + k0 + lak);
        float4 wv0 = *(const float4*)(W + (size_t)(k0 + lwk) * HID_ + bn + lwn);
        float4 wv1 = *(const float4*)(W + (size_t)(k0 + lwk) * HID_ + bn + lwn + 4);
        As[lak + 0][lam] = av.x;
        As[lak + 1][lam] = av.y;
        As[lak + 2][lam] = av.z;
        As[lak + 3][lam] = av.w;
        *(float4*)&Ws[lwk][lwn]     = wv0;
        *(float4*)&Ws[lwk][lwn + 4] = wv1;
        __syncthreads();
#pragma unroll
        for (int kk = 0; kk < 16; ++kk) {
            float4 a4 = *(const float4*)&As[kk][tr];
            float4 b0 = *(const float4*)&Ws[kk][tc4];
            float4 b1 = *(const float4*)&Ws[kk][64 + tc4];
            float aa[4] = {a4.x, a4.y, a4.z, a4.w};
            float bb[8] = {b0.x, b0.y, b0.z, b0.w, b1.x, b1.y, b1.z, b1.w};
#pragma unroll
            for (int i = 0; i < 4; ++i)
#pragma unroll
                for (int j = 0; j < 8; ++j)
                    acc[i][j] += aa[i] * bb[j];
        }
        __syncthreads();
    }

#pragma unroll
    for (int i = 0; i < 4; ++i) {
        float4 o0 = make_float4(acc[i][0], acc[i][1], acc[i][2], acc[i][3]);
        float4 o1 = make_float4(acc[i][4], acc[i][5], acc[i][6], acc[i][7]);
        *(float4*)(C + (size_t)(bm + tr + i) * HID_ + bn + tc4)      = o0;
        *(float4*)(C + (size_t)(bm + tr + i) * HID_ + bn + 64 + tc4) = o1;
    }
}

// ---------------------------------------------------------------------------
// Wo GEMM (unchanged)
// ---------------------------------------------------------------------------
__global__ __launch_bounds__(256) void gemm_wo(
    const float* __restrict__ A, const float* __restrict__ W,
    float* __restrict__ C)
{
    __shared__ __align__(16) float As[16][68];
    __shared__ __align__(16) float Ws[16][64];

    const int t  = threadIdx.x;
    const int bm = blockIdx.y * 64;
    const int bn = blockIdx.x * 64;

    const int tr  = (t >> 4) * 4;
    const int tc4 = (t & 15) * 4;

    float acc[4][4];
#pragma unroll
    for (int i = 0; i < 4; ++i)
#pragma unroll
        for (int j = 0; j < 4; ++j) acc[i][j] = 0.f;

    const int lam = t >> 2;
    const int lak = (t & 3) * 4;
    const int lwk = t >> 4;
    const int lwn = (t & 15) * 4;

    for (int k0 = 0; k0 < HID_; k0 += 16) {
        float4 av = *(const float4*)(A + (size_t)(bm + lam) * HID_ + k0 + lak);
        float4 wv = *(const float4*)(W + (size_t)(k0 + lwk) * HID_ + bn + lwn);
        As[lak + 0][lam] = av.x;
        As[lak + 1][lam] = av.y;
        As[lak + 2][lam] = av.z;
        As[lak + 3][lam] = av.w;
        *(float4*)&Ws[lwk][lwn] = wv;
        __syncthreads();
#pragma unroll
        for (int kk = 0; kk < 16; ++kk) {
            float4 a4 = *(const float4*)&As[kk][tr];
            float4 b4 = *(const float4*)&Ws[kk][tc4];
            float aa[4] = {a4.x, a4.y, a4.z, a4.w};
            float bb[4] = {b4.x, b4.y, b4.z, b4.w};
#pragma unroll
            for (int i = 0; i < 4; ++i)
#pragma unroll
                for (int j = 0; j < 4; ++j)
                    acc[i][j] += aa[i] * bb[j];
        }
        __syncthreads();
    }

#pragma unroll
    for (int i = 0; i < 4; ++i)
        *(float4*)(C + (size_t)(bm + tr + i) * HID_ + bn + tc4) =
            make_float4(acc[i][0], acc[i][1], acc[i][2], acc[i][3]);
}

// ---------------------------------------------------------------------------
// alpha/beta projections (unchanged)
// ---------------------------------------------------------------------------
__global__ __launch_bounds__(256) void ab_kernel(
    const float* __restrict__ x,
    const float* __restrict__ Wa, const float* __restrict__ ba,
    const float* __restrict__ Wb, const float* __restrict__ bbias,
    float* __restrict__ alpha, float* __restrict__ beta)
{
    int gid = blockIdx.x * 256 + threadIdx.x;
    int row = gid >> 5;
    int c   = gid & 31;
    const float* w = (c < 16) ? (Wa + c) : (Wb + (c - 16));
    float bias     = (c < 16) ? ba[c] : bbias[c - 16];
    const float* xr = x + (size_t)row * HID_;
    float s = 0.f;
#pragma unroll 4
    for (int k = 0; k < HID_; ++k) s += xr[k] * w[(size_t)k * NH_];
    float val = 1.f / (1.f + expf(-(s + bias)));
    if (c < 16) alpha[row * NH_ + c]       = val;
    else        beta[row * NH_ + (c - 16)] = val;
}

// ---------------------------------------------------------------------------
// l2norm(q), l2norm(k), tanh(v) — DPP reduce + readlane broadcast
// ---------------------------------------------------------------------------
__global__ __launch_bounds__(256) void norm_kernel(
    float* __restrict__ q, float* __restrict__ k, float* __restrict__ v)
{
    int gid = blockIdx.x * 256 + threadIdx.x;

    float qv = q[gid];
    float qs = wave_sum_lane63(qv * qv);
    qs = __int_as_float(__builtin_amdgcn_readlane(__float_as_int(qs), 63));
    q[gid] = qv / fmaxf(sqrtf(qs), EPS_);

    float kv = k[gid];
    float ks = wave_sum_lane63(kv * kv);
    ks = __int_as_float(__builtin_amdgcn_readlane(__float_as_int(ks), 63));
    k[gid] = kv / fmaxf(sqrtf(ks), EPS_);

    v[gid] = tanhf(v[gid]);
}

// ---------------------------------------------------------------------------
// Scan: one wave per (b,h,v) state row; lane = column. DPP reductions,
// 4-step iterations with distance-8 prefetch, XCD-local block decode
// (v = bid>>5, bh = bid&31 -> all 64 v-waves of a (b,h) share bid%8 -> XCD).
// ---------------------------------------------------------------------------
__global__ __launch_bounds__(64) void scan_kernel(
    const float* __restrict__ qn, const float* __restrict__ kn,
    const float* __restrict__ vt,
    const float* __restrict__ alpha, const float* __restrict__ beta,
    const int* __restrict__ mask,
    const float* __restrict__ state0,
    float* __restrict__ y, float* __restrict__ state_out)
{
    const int bid  = blockIdx.x;
    const int v    = bid >> 5;        // 0..63
    const int bh   = bid & 31;        // xcd = bid%8 = bh%8
    const int b    = bh >> 4;
    const int h    = bh & 15;
    const int lane = threadIdx.x;     // column
    const int gid  = bh * 64 + v;     // state row index

    float st = state0[(size_t)gid * 64 + lane];

    const size_t rowbase = (size_t)b * S_ * HID_ + h * 64;
    const float* kp = kn + rowbase + lane;
    const float* qp = qn + rowbase + lane;
    const float* vp = vt + rowbase + v;
    const float* ap = alpha + (size_t)b * S_ * NH_ + h;
    const float* bp = beta  + (size_t)b * S_ * NH_ + h;
    const int*   mp = mask  + b * S_;
    float*       yp = y + rowbase + v;

    // pipeline register sets: cur = steps t..t+3, nxt = t+4..t+7
    float kc[4], qc[4], vc[4], ac[4], bc[4]; int mc[4];
    float kx[4], qx[4], vx[4], ax[4], bx[4]; int mx[4];

#pragma unroll
    for (int j = 0; j < 4; ++j) {
        kc[j] = kp[(size_t)j * HID_];       qc[j] = qp[(size_t)j * HID_];
        vc[j] = vp[(size_t)j * HID_];
        ac[j] = ap[(size_t)j * NH_];        bc[j] = bp[(size_t)j * NH_];
        mc[j] = mp[j];
        kx[j] = kp[(size_t)(4 + j) * HID_]; qx[j] = qp[(size_t)(4 + j) * HID_];
        vx[j] = vp[(size_t)(4 + j) * HID_];
        ax[j] = ap[(size_t)(4 + j) * NH_];  bx[j] = bp[(size_t)(4 + j) * NH_];
        mx[j] = mp[4 + j];
    }

    for (int t = 0; t < S_; t += 4) {
        // prefetch steps t+8..t+11 (distance ~2 iterations)
        float kt[4], qt[4], vtl[4], at[4], btl[4]; int mt[4];
#pragma unroll
        for (int j = 0; j < 4; ++j) {
            int ti = t + 8 + j; if (ti >= S_) ti = S_ - 1;
            kt[j]  = kp[(size_t)ti * HID_];
            qt[j]  = qp[(size_t)ti * HID_];
            vtl[j] = vp[(size_t)ti * HID_];
            at[j]  = ap[(size_t)ti * NH_];
            btl[j] = bp[(size_t)ti * NH_];
            mt[j]  = mp[ti];
        }

#pragma unroll
        for (int j = 0; j < 4; ++j) {
            // read = st . k  (DPP reduce -> lane63 -> SGPR broadcast)
            float r  = wave_sum_lane63(st * kc[j]);
            float rs = __int_as_float(__builtin_amdgcn_readlane(__float_as_int(r), 63));
            if (mc[j]) {
                float cf = bc[j] * (vc[j] - rs);
                st = fminf(fmaxf(ac[j] * st + cf * kc[j], -CLIP_), CLIP_);
            }
            // y = st . q  (no broadcast needed; lane 63 stores)
            float yv = wave_sum_lane63(st * qc[j]);
            if (lane == 63) yp[(size_t)(t + j) * HID_] = mc[j] ? yv : 0.f;
        }

#pragma unroll
        for (int j = 0; j < 4; ++j) {
            kc[j] = kx[j]; qc[j] = qx[j]; vc[j] = vx[j];
            ac[j] = ax[j]; bc[j] = bx[j]; mc[j] = mx[j];
            kx[j] = kt[j]; qx[j] = qt[j]; vx[j] = vtl[j];
            ax[j] = at[j]; bx[j] = btl[j]; mx[j] = mt[j];
        }
    }

    state_out[(size_t)gid * 64 + lane] = st;
}

// ---------------------------------------------------------------------------
// launch
// ---------------------------------------------------------------------------
extern "C" void kernel_launch(void* const* d_in, const int* in_sizes, int n_in,
                              void* d_out, int out_size, void* d_ws, size_t ws_size,
                              hipStream_t stream)
{
    (void)in_sizes; (void)n_in; (void)out_size; (void)ws_size;

    const float* x      = (const float*)d_in[0];
    const float* Wq     = (const float*)d_in[1];
    const float* Wk     = (const float*)d_in[2];
    const float* Wv     = (const float*)d_in[3];
    const float* Wa     = (const float*)d_in[4];
    const float* ba     = (const float*)d_in[5];
    const float* Wb     = (const float*)d_in[6];
    const float* bb     = (const float*)d_in[7];
    const float* Wo     = (const float*)d_in[8];
    const float* state0 = (const float*)d_in[9];
    const int*   mask   = (const int*)d_in[10];

    float* out = (float*)d_out;
    float* ws  = (float*)d_ws;

    float* q     = ws;
    float* k     = ws + 2097152;
    float* v     = ws + 4194304;
    float* alpha = ws + 6291456;
    float* beta  = ws + 6324224;
    float* y     = ws + 6356992;

    dim3 gqkv(8, 32, 3);   // N/128, M/64, {q,k,v}
    gemm_qkv<<<gqkv, 256, 0, stream>>>(x, Wq, Wk, Wv, q, k, v);
    ab_kernel<<<M_ * 32 / 256, 256, 0, stream>>>(x, Wa, ba, Wb, bb, alpha, beta);
    norm_kernel<<<M_ * HID_ / 256, 256, 0, stream>>>(q, k, v);
    scan_kernel<<<B_ * NH_ * D_, 64, 0, stream>>>(q, k, v, alpha, beta, mask, state0,
                                                  y, out + (size_t)M_ * HID_);
    dim3 gwo(16, 32);      // N/64, M/64
    gemm_wo<<<gwo, 256, 0, stream>>>(y, Wo, out);
}